// Round 1
// baseline (1072.166 us; speedup 1.0000x reference)
//
#include <hip/hip_runtime.h>
#include <hip/hip_bf16.h>

#define D 128

typedef __attribute__((ext_vector_type(8))) __bf16 bf16x8;
typedef __attribute__((ext_vector_type(4))) float f32x4;
typedef __attribute__((ext_vector_type(4))) short s16x4;

static __device__ __forceinline__ short f2bf(float f) {
    union { float f; unsigned u; } in; in.f = f;
    unsigned u = in.u;
    u += 0x7fffu + ((u >> 16) & 1u);   // round-to-nearest-even
    return (short)(u >> 16);
}

// ---- degree histogram over dst ----
__global__ void k_count(const int* __restrict__ dst, int* __restrict__ counts, int E) {
    int i = blockIdx.x * blockDim.x + threadIdx.x;
    if (i < E) atomicAdd(&counts[dst[i]], 1);
}

// ---- dinv = rsqrt(indeg + 1)  (self-loop makes deg >= 1 always) ----
__global__ void k_dinv(const int* __restrict__ counts, float* __restrict__ dinv, int N) {
    int i = blockIdx.x * blockDim.x + threadIdx.x;
    if (i < N) dinv[i] = rsqrtf((float)counts[i] + 1.0f);
}

// ---- 3-kernel exclusive scan of counts -> row_ptr ----
__global__ void k_scan1(const int* __restrict__ counts, int* __restrict__ excl,
                        int* __restrict__ bsums, int N) {
    __shared__ int s[256];
    int i = blockIdx.x * 256 + threadIdx.x;
    int v = (i < N) ? counts[i] : 0;
    s[threadIdx.x] = v;
    __syncthreads();
    for (int off = 1; off < 256; off <<= 1) {
        int t = (threadIdx.x >= off) ? s[threadIdx.x - off] : 0;
        __syncthreads();
        s[threadIdx.x] += t;
        __syncthreads();
    }
    if (i < N) excl[i] = s[threadIdx.x] - v;
    if (threadIdx.x == 255) bsums[blockIdx.x] = s[255];
}

__global__ void k_scan2(const int* __restrict__ bsums, int* __restrict__ boffs, int nb) {
    __shared__ int s[512];
    int t = threadIdx.x;
    int v = (t < nb) ? bsums[t] : 0;
    s[t] = v;
    __syncthreads();
    for (int off = 1; off < 512; off <<= 1) {
        int x = (t >= off) ? s[t - off] : 0;
        __syncthreads();
        s[t] += x;
        __syncthreads();
    }
    if (t < nb) boffs[t] = s[t] - v;
}

__global__ void k_scan3(int* __restrict__ row_ptr, int* __restrict__ cursor,
                        const int* __restrict__ boffs, int N, int E) {
    int i = blockIdx.x * 256 + threadIdx.x;
    if (i < N) {
        int r = row_ptr[i] + boffs[blockIdx.x];
        row_ptr[i] = r;
        cursor[i] = r;
    }
    if (i == 0) row_ptr[N] = E;
}

// ---- scatter edges into CSR slots ----
__global__ void k_fill(const int* __restrict__ src, const int* __restrict__ dst,
                       int* __restrict__ cursor, int* __restrict__ csr_src, int E) {
    int i = blockIdx.x * blockDim.x + threadIdx.x;
    if (i < E) {
        int slot = atomicAdd(&cursor[dst[i]], 1);
        csr_src[slot] = src[i];
    }
}

// ---- fp32 -> bf16 convert (x into GEMM input buffer) ----
__global__ void k_cvt_x(const float* __restrict__ x, short* __restrict__ xb, int total4) {
    int i = blockIdx.x * blockDim.x + threadIdx.x;
    if (i < total4) {
        float4 v = ((const float4*)x)[i];
        s16x4 o;
        o.x = f2bf(v.x); o.y = f2bf(v.y); o.z = f2bf(v.z); o.w = f2bf(v.w);
        ((s16x4*)xb)[i] = o;
    }
}

// ---- conv_w: fp32 [L][k][n] -> bf16 transposed [L][n][k] ----
__global__ void k_cvt_w(const float* __restrict__ W, short* __restrict__ Wt, int total) {
    int i = blockIdx.x * blockDim.x + threadIdx.x;
    if (i < total) {
        int l = i >> 14;
        int rem = i & 16383;
        int n = rem >> 7;
        int k = rem & 127;
        Wt[i] = f2bf(W[(l << 14) + (k << 7) + n]);
    }
}

// ---- bf16 MFMA GEMM: C[N x 128] = A[N x 128] * W  (Wt is W transposed [n][k]) ----
__global__ __launch_bounds__(256) void k_gemm(const short* __restrict__ A,
                                              const short* __restrict__ Wt,
                                              float* __restrict__ C, int N) {
    const int wave = threadIdx.x >> 6;
    const int lane = threadIdx.x & 63;
    const int m_base = blockIdx.x * 128 + wave * 32;
    const int lr = lane & 15;
    const int lq = lane >> 4;

    bf16x8 afrag[2][4];
    #pragma unroll
    for (int rt = 0; rt < 2; rt++) {
        int m = m_base + rt * 16 + lr;
        if (m >= N) m = N - 1;               // clamp: garbage rows only affect guarded stores
        const short* ap = A + (size_t)m * D + lq * 8;
        #pragma unroll
        for (int kt = 0; kt < 4; kt++)
            afrag[rt][kt] = *(const bf16x8*)(ap + kt * 32);
    }

    f32x4 acc[2][8];
    #pragma unroll
    for (int rt = 0; rt < 2; rt++)
        #pragma unroll
        for (int nt = 0; nt < 8; nt++) {
            f32x4 z = {0.f, 0.f, 0.f, 0.f};
            acc[rt][nt] = z;
        }

    const short* bp = Wt + lr * D + lq * 8;
    #pragma unroll
    for (int nt = 0; nt < 8; nt++) {
        #pragma unroll
        for (int kt = 0; kt < 4; kt++) {
            bf16x8 b = *(const bf16x8*)(bp + nt * 16 * D + kt * 32);
            acc[0][nt] = __builtin_amdgcn_mfma_f32_16x16x32_bf16(afrag[0][kt], b, acc[0][nt], 0, 0, 0);
            acc[1][nt] = __builtin_amdgcn_mfma_f32_16x16x32_bf16(afrag[1][kt], b, acc[1][nt], 0, 0, 0);
        }
    }

    // C/D layout: col = lane&15, row = (lane>>4)*4 + reg   [measured m89/m91]
    #pragma unroll
    for (int rt = 0; rt < 2; rt++) {
        int row0 = m_base + rt * 16 + lq * 4;
        #pragma unroll
        for (int nt = 0; nt < 8; nt++) {
            int col = nt * 16 + lr;
            #pragma unroll
            for (int i2 = 0; i2 < 4; i2++) {
                int r = row0 + i2;
                if (r < N) C[(size_t)r * D + col] = acc[rt][nt][i2];
            }
        }
    }
}

// ---- pull-aggregation: h_out[i] = relu(b + dinv[i]*(sum_e dinv[s]*hw[s] + dinv[i]*hw[i])) ----
// mode 0: write bf16 h for next layer's GEMM. mode 1: fused global max/sum/count pooling.
__global__ void k_aggregate(const float* __restrict__ hw, const int* __restrict__ row_ptr,
                            const int* __restrict__ csr_src, const float* __restrict__ dinv,
                            const float* __restrict__ bias, short* __restrict__ hb,
                            const int* __restrict__ batch, float* __restrict__ gmax,
                            float* __restrict__ gsum, int* __restrict__ gcnt,
                            int N, int mode) {
    int i = blockIdx.x;
    int c = threadIdx.x;
    float di = dinv[i];
    float acc = di * hw[(size_t)i * D + c];
    int start = row_ptr[i], end = row_ptr[i + 1];

    __shared__ int s_src[128];
    __shared__ float s_w[128];
    for (int base = start; base < end; base += 128) {
        int cnt = end - base;
        if (cnt > 128) cnt = 128;
        if (c < cnt) {
            int s = csr_src[base + c];
            s_src[c] = s;
            s_w[c] = dinv[s];
        }
        __syncthreads();
        for (int j = 0; j < cnt; j++)
            acc += s_w[j] * hw[(size_t)s_src[j] * D + c];
        __syncthreads();
    }

    float val = fmaxf(di * acc + bias[c], 0.0f);
    if (mode == 0) {
        hb[(size_t)i * D + c] = f2bf(val);
    } else {
        int g = batch[i];
        atomicMax((int*)&gmax[g * D + c], __float_as_int(val));  // val >= 0: int order == float order
        atomicAdd(&gsum[g * D + c], val);
        if (c == 0) atomicAdd(&gcnt[g], 1);
    }
}

// ---- final: out[g] = [gmax, gsum/cnt, gsum] @ out_w + out_b ----
__global__ void k_final(const float* __restrict__ gmax, const float* __restrict__ gsum,
                        const int* __restrict__ gcnt, const float* __restrict__ ow,
                        const float* __restrict__ ob, float* __restrict__ out) {
    int g = blockIdx.x;
    int t = threadIdx.x;  // 64
    float part[10];
    #pragma unroll
    for (int o = 0; o < 10; o++) part[o] = 0.f;
    float invc = 1.0f / fmaxf((float)gcnt[g], 1.0f);
    for (int k = t; k < 3 * D; k += 64) {
        float pk;
        if (k < D) pk = gmax[g * D + k];
        else if (k < 2 * D) pk = gsum[g * D + (k - D)] * invc;
        else pk = gsum[g * D + (k - 2 * D)];
        const float* w = ow + k * 10;
        #pragma unroll
        for (int o = 0; o < 10; o++) part[o] += pk * w[o];
    }
    #pragma unroll
    for (int off = 32; off > 0; off >>= 1)
        #pragma unroll
        for (int o = 0; o < 10; o++) part[o] += __shfl_down(part[o], off, 64);
    if (t == 0)
        #pragma unroll
        for (int o = 0; o < 10; o++) out[g * 10 + o] = part[o] + ob[o];
}

extern "C" void kernel_launch(void* const* d_in, const int* in_sizes, int n_in,
                              void* d_out, int out_size, void* d_ws, size_t ws_size,
                              hipStream_t stream) {
    const float* x     = (const float*)d_in[0];
    const int*   ei    = (const int*)d_in[1];
    const int*   batch = (const int*)d_in[2];
    const float* convw = (const float*)d_in[3];
    const float* convb = (const float*)d_in[4];
    const float* outw  = (const float*)d_in[5];
    const float* outb  = (const float*)d_in[6];
    float* out = (float*)d_out;

    const int N = in_sizes[0] / D;        // 100000
    const int E = in_sizes[1] / 2;        // 1600000
    const int L = in_sizes[3] / (D * D);  // 3
    const int B = out_size / 10;          // 256

    const int* src = ei;
    const int* dst = ei + E;

    char* p = (char*)d_ws;
    auto alloc = [&](size_t bytes) { char* r = p; p += (bytes + 255) & ~255ull; return r; };
    short* xb      = (short*)alloc((size_t)N * D * 2);      // bf16 h buffer (GEMM input)
    float* hw      = (float*)alloc((size_t)N * D * 4);      // fp32 GEMM output
    short* Wt      = (short*)alloc((size_t)L * D * D * 2);  // bf16 W^T
    int*   counts  = (int*)alloc((size_t)N * 4);
    int*   row_ptr = (int*)alloc(((size_t)N + 1) * 4);
    int*   cursor  = (int*)alloc((size_t)N * 4);
    int*   csr_src = (int*)alloc((size_t)E * 4);
    int*   bsums   = (int*)alloc(512 * 4);
    int*   boffs   = (int*)alloc(512 * 4);
    float* dinv    = (float*)alloc((size_t)N * 4);
    float* gmax    = (float*)alloc((size_t)B * D * 4);
    float* gsum    = (float*)alloc((size_t)B * D * 4);
    int*   gcnt    = (int*)alloc((size_t)B * 4);

    hipMemsetAsync(counts, 0, (size_t)N * 4, stream);
    hipMemsetAsync(gmax, 0, (size_t)B * D * 4, stream);
    hipMemsetAsync(gsum, 0, (size_t)B * D * 4, stream);
    hipMemsetAsync(gcnt, 0, (size_t)B * 4, stream);

    const int nb = (N + 255) / 256;
    k_count<<<(E + 255) / 256, 256, 0, stream>>>(dst, counts, E);
    k_dinv<<<nb, 256, 0, stream>>>(counts, dinv, N);
    k_scan1<<<nb, 256, 0, stream>>>(counts, row_ptr, bsums, N);
    k_scan2<<<1, 512, 0, stream>>>(bsums, boffs, nb);
    k_scan3<<<nb, 256, 0, stream>>>(row_ptr, cursor, boffs, N, E);
    k_fill<<<(E + 255) / 256, 256, 0, stream>>>(src, dst, cursor, csr_src, E);
    k_cvt_x<<<((N * D / 4) + 255) / 256, 256, 0, stream>>>(x, xb, N * D / 4);
    k_cvt_w<<<((L * D * D) + 255) / 256, 256, 0, stream>>>(convw, Wt, L * D * D);

    const int gblocks = (N + 127) / 128;
    for (int l = 0; l < L; l++) {
        k_gemm<<<gblocks, 256, 0, stream>>>(xb, Wt + l * D * D, hw, N);
        k_aggregate<<<N, 128, 0, stream>>>(hw, row_ptr, csr_src, dinv, convb + (size_t)l * D,
                                           xb, batch, gmax, gsum, gcnt, N,
                                           (l == L - 1) ? 1 : 0);
    }
    k_final<<<B, 64, 0, stream>>>(gmax, gsum, gcnt, outw, outb, out);
}

// Round 2
// 1015.487 us; speedup vs baseline: 1.0558x; 1.0558x over previous
//
#include <hip/hip_runtime.h>
#include <hip/hip_bf16.h>

#define D 128

typedef __attribute__((ext_vector_type(8))) __bf16 bf16x8;
typedef __attribute__((ext_vector_type(4))) float f32x4;
typedef __attribute__((ext_vector_type(4))) short s16x4;
typedef __attribute__((ext_vector_type(8))) short s16x8;

static __device__ __forceinline__ short f2bf(float f) {
    union { float f; unsigned u; } in; in.f = f;
    unsigned u = in.u;
    u += 0x7fffu + ((u >> 16) & 1u);   // round-to-nearest-even
    return (short)(u >> 16);
}

// ---- degree histogram over dst ----
__global__ void k_count(const int* __restrict__ dst, int* __restrict__ counts, int E) {
    int i = blockIdx.x * blockDim.x + threadIdx.x;
    if (i < E) atomicAdd(&counts[dst[i]], 1);
}

// ---- dinv = rsqrt(indeg + 1) ----
__global__ void k_dinv(const int* __restrict__ counts, float* __restrict__ dinv, int N) {
    int i = blockIdx.x * blockDim.x + threadIdx.x;
    if (i < N) dinv[i] = rsqrtf((float)counts[i] + 1.0f);
}

// ---- graph node counts (for mean pooling) ----
__global__ void k_gcnt(const int* __restrict__ batch, int* __restrict__ gcnt, int N) {
    int i = blockIdx.x * blockDim.x + threadIdx.x;
    if (i < N) atomicAdd(&gcnt[batch[i]], 1);
}

// ---- 3-kernel exclusive scan of counts -> row_ptr ----
__global__ void k_scan1(const int* __restrict__ counts, int* __restrict__ excl,
                        int* __restrict__ bsums, int N) {
    __shared__ int s[256];
    int i = blockIdx.x * 256 + threadIdx.x;
    int v = (i < N) ? counts[i] : 0;
    s[threadIdx.x] = v;
    __syncthreads();
    for (int off = 1; off < 256; off <<= 1) {
        int t = (threadIdx.x >= off) ? s[threadIdx.x - off] : 0;
        __syncthreads();
        s[threadIdx.x] += t;
        __syncthreads();
    }
    if (i < N) excl[i] = s[threadIdx.x] - v;
    if (threadIdx.x == 255) bsums[blockIdx.x] = s[255];
}

__global__ void k_scan2(const int* __restrict__ bsums, int* __restrict__ boffs, int nb) {
    __shared__ int s[512];
    int t = threadIdx.x;
    int v = (t < nb) ? bsums[t] : 0;
    s[t] = v;
    __syncthreads();
    for (int off = 1; off < 512; off <<= 1) {
        int x = (t >= off) ? s[t - off] : 0;
        __syncthreads();
        s[t] += x;
        __syncthreads();
    }
    if (t < nb) boffs[t] = s[t] - v;
}

__global__ void k_scan3(int* __restrict__ row_ptr, int* __restrict__ cursor,
                        const int* __restrict__ boffs, int N, int E) {
    int i = blockIdx.x * 256 + threadIdx.x;
    if (i < N) {
        int r = row_ptr[i] + boffs[blockIdx.x];
        row_ptr[i] = r;
        cursor[i] = r;
    }
    if (i == 0) row_ptr[N] = E;
}

// ---- scatter edges into CSR slots ----
__global__ void k_fill(const int* __restrict__ src, const int* __restrict__ dst,
                       int* __restrict__ cursor, int* __restrict__ csr_src, int E) {
    int i = blockIdx.x * blockDim.x + threadIdx.x;
    if (i < E) {
        int slot = atomicAdd(&cursor[dst[i]], 1);
        csr_src[slot] = src[i];
    }
}

// ---- x' = dinv[i] * x  -> bf16 (pre-scaled feature rows) ----
__global__ void k_cvt_x(const float* __restrict__ x, const float* __restrict__ dinv,
                        short* __restrict__ xb, int total4) {
    int i = blockIdx.x * blockDim.x + threadIdx.x;
    if (i < total4) {
        float d = dinv[i >> 5];              // D/4 = 32 float4 per row
        float4 v = ((const float4*)x)[i];
        s16x4 o;
        o.x = f2bf(v.x * d); o.y = f2bf(v.y * d);
        o.z = f2bf(v.z * d); o.w = f2bf(v.w * d);
        ((s16x4*)xb)[i] = o;
    }
}

// ---- conv_w: fp32 [L][k][n] -> bf16 transposed [L][n][k] ----
__global__ void k_cvt_w(const float* __restrict__ W, short* __restrict__ Wt, int total) {
    int i = blockIdx.x * blockDim.x + threadIdx.x;
    if (i < total) {
        int l = i >> 14;
        int rem = i & 16383;
        int n = rem >> 7;
        int k = rem & 127;
        Wt[i] = f2bf(W[(l << 14) + (k << 7) + n]);
    }
}

// ---- pull-aggregation on bf16 rows: g[i] = dinv[i] * (h'[i] + sum_edges h'[src]) ----
// h' rows are pre-scaled by dinv[src]. One wave per node; 4 groups of 16 lanes
// process 4 edges concurrently; 2 accumulator chains per group for ILP.
__global__ __launch_bounds__(256) void k_aggregate(
    const short* __restrict__ hb, const int* __restrict__ row_ptr,
    const int* __restrict__ csr_src, const float* __restrict__ dinv,
    short* __restrict__ g, int N)
{
    const int w = threadIdx.x >> 6;
    const int lane = threadIdx.x & 63;
    const int i = blockIdx.x * 4 + w;
    if (i >= N) return;
    const int group = lane >> 4;
    const int lg = lane & 15;
    const int off = lg * 8;

    float accA[8], accB[8];
    #pragma unroll
    for (int k = 0; k < 8; k++) { accA[k] = 0.f; accB[k] = 0.f; }

    const float di = dinv[i];
    const int start = row_ptr[i], end = row_ptr[i + 1];

    if (group == 0) {  // self-loop term, added once
        bf16x8 v = *(const bf16x8*)(hb + (size_t)i * D + off);
        #pragma unroll
        for (int k = 0; k < 8; k++) accA[k] += (float)v[k];
    }

    int e = start + group;
    int sA = (e < end) ? csr_src[e] : -1;
    int sB = (e + 4 < end) ? csr_src[e + 4] : -1;
    while (sB >= 0) {
        bf16x8 vA = *(const bf16x8*)(hb + (size_t)sA * D + off);
        bf16x8 vB = *(const bf16x8*)(hb + (size_t)sB * D + off);
        e += 8;
        sA = (e < end) ? csr_src[e] : -1;
        sB = (e + 4 < end) ? csr_src[e + 4] : -1;
        #pragma unroll
        for (int k = 0; k < 8; k++) { accA[k] += (float)vA[k]; accB[k] += (float)vB[k]; }
    }
    if (sA >= 0) {
        bf16x8 vA = *(const bf16x8*)(hb + (size_t)sA * D + off);
        #pragma unroll
        for (int k = 0; k < 8; k++) accA[k] += (float)vA[k];
    }

    // merge chains + cross-group reduction (lanes {l, l^16, l^32, l^48})
    #pragma unroll
    for (int k = 0; k < 8; k++) {
        float t = accA[k] + accB[k];
        t += __shfl_xor(t, 16, 64);
        t += __shfl_xor(t, 32, 64);
        accA[k] = t * di;
    }
    if (group == 0) {
        s16x8 o;
        #pragma unroll
        for (int k = 0; k < 8; k++) o[k] = f2bf(accA[k]);
        *(s16x8*)(g + (size_t)i * D + off) = o;
    }
}

// ---- bf16 MFMA GEMM: C = A[N x 128] * W, fused epilogue.
// mode 0: hb_out[r] = bf16( relu(C + b) * dinv[r] )  (pre-scaled next-layer rows)
// mode 1: pooling atomics on relu(C + b)
__global__ __launch_bounds__(256) void k_gemm(const short* __restrict__ A,
                                              const short* __restrict__ Wt,
                                              const float* __restrict__ bias,
                                              const float* __restrict__ dinv,
                                              short* __restrict__ hb_out,
                                              const int* __restrict__ batch,
                                              float* __restrict__ gmax,
                                              float* __restrict__ gsum,
                                              int N, int mode) {
    const int wave = threadIdx.x >> 6;
    const int lane = threadIdx.x & 63;
    const int m_base = blockIdx.x * 128 + wave * 32;
    const int lr = lane & 15;
    const int lq = lane >> 4;

    bf16x8 afrag[2][4];
    #pragma unroll
    for (int rt = 0; rt < 2; rt++) {
        int m = m_base + rt * 16 + lr;
        if (m >= N) m = N - 1;
        const short* ap = A + (size_t)m * D + lq * 8;
        #pragma unroll
        for (int kt = 0; kt < 4; kt++)
            afrag[rt][kt] = *(const bf16x8*)(ap + kt * 32);
    }

    f32x4 acc[2][8];
    #pragma unroll
    for (int rt = 0; rt < 2; rt++)
        #pragma unroll
        for (int nt = 0; nt < 8; nt++) {
            f32x4 z = {0.f, 0.f, 0.f, 0.f};
            acc[rt][nt] = z;
        }

    const short* bp = Wt + lr * D + lq * 8;
    #pragma unroll
    for (int nt = 0; nt < 8; nt++) {
        #pragma unroll
        for (int kt = 0; kt < 4; kt++) {
            bf16x8 b = *(const bf16x8*)(bp + nt * 16 * D + kt * 32);
            acc[0][nt] = __builtin_amdgcn_mfma_f32_16x16x32_bf16(afrag[0][kt], b, acc[0][nt], 0, 0, 0);
            acc[1][nt] = __builtin_amdgcn_mfma_f32_16x16x32_bf16(afrag[1][kt], b, acc[1][nt], 0, 0, 0);
        }
    }

    // C/D layout: col = lane&15, row = (lane>>4)*4 + reg
    float bcol[8];
    #pragma unroll
    for (int nt = 0; nt < 8; nt++) bcol[nt] = bias[nt * 16 + lr];

    #pragma unroll
    for (int rt = 0; rt < 2; rt++) {
        int row0 = m_base + rt * 16 + lq * 4;
        #pragma unroll
        for (int i2 = 0; i2 < 4; i2++) {
            int r = row0 + i2;
            if (r < N) {
                if (mode == 0) {
                    float dr = dinv[r];
                    #pragma unroll
                    for (int nt = 0; nt < 8; nt++) {
                        int col = nt * 16 + lr;
                        float val = fmaxf(acc[rt][nt][i2] + bcol[nt], 0.0f);
                        hb_out[(size_t)r * D + col] = f2bf(val * dr);
                    }
                } else {
                    int gb = batch[r] * D;
                    #pragma unroll
                    for (int nt = 0; nt < 8; nt++) {
                        int col = nt * 16 + lr;
                        float val = fmaxf(acc[rt][nt][i2] + bcol[nt], 0.0f);
                        atomicMax((int*)&gmax[gb + col], __float_as_int(val)); // val>=0
                        atomicAdd(&gsum[gb + col], val);
                    }
                }
            }
        }
    }
}

// ---- final: out[g] = [gmax, gsum/cnt, gsum] @ out_w + out_b ----
__global__ void k_final(const float* __restrict__ gmax, const float* __restrict__ gsum,
                        const int* __restrict__ gcnt, const float* __restrict__ ow,
                        const float* __restrict__ ob, float* __restrict__ out) {
    int g = blockIdx.x;
    int t = threadIdx.x;  // 64
    float part[10];
    #pragma unroll
    for (int o = 0; o < 10; o++) part[o] = 0.f;
    float invc = 1.0f / fmaxf((float)gcnt[g], 1.0f);
    for (int k = t; k < 3 * D; k += 64) {
        float pk;
        if (k < D) pk = gmax[g * D + k];
        else if (k < 2 * D) pk = gsum[g * D + (k - D)] * invc;
        else pk = gsum[g * D + (k - 2 * D)];
        const float* w = ow + k * 10;
        #pragma unroll
        for (int o = 0; o < 10; o++) part[o] += pk * w[o];
    }
    #pragma unroll
    for (int off = 32; off > 0; off >>= 1)
        #pragma unroll
        for (int o = 0; o < 10; o++) part[o] += __shfl_down(part[o], off, 64);
    if (t == 0)
        #pragma unroll
        for (int o = 0; o < 10; o++) out[g * 10 + o] = part[o] + ob[o];
}

extern "C" void kernel_launch(void* const* d_in, const int* in_sizes, int n_in,
                              void* d_out, int out_size, void* d_ws, size_t ws_size,
                              hipStream_t stream) {
    const float* x     = (const float*)d_in[0];
    const int*   ei    = (const int*)d_in[1];
    const int*   batch = (const int*)d_in[2];
    const float* convw = (const float*)d_in[3];
    const float* convb = (const float*)d_in[4];
    const float* outw  = (const float*)d_in[5];
    const float* outb  = (const float*)d_in[6];
    float* out = (float*)d_out;

    const int N = in_sizes[0] / D;        // 100000
    const int E = in_sizes[1] / 2;        // 1600000
    const int L = in_sizes[3] / (D * D);  // 3
    const int B = out_size / 10;          // 256

    const int* src = ei;
    const int* dst = ei + E;

    char* p = (char*)d_ws;
    auto alloc = [&](size_t bytes) { char* r = p; p += (bytes + 255) & ~255ull; return r; };
    short* hb      = (short*)alloc((size_t)N * D * 2);      // bf16 pre-scaled feature rows
    short* gbuf    = (short*)alloc((size_t)N * D * 2);      // bf16 aggregated rows (GEMM input)
    short* Wt      = (short*)alloc((size_t)L * D * D * 2);  // bf16 W^T
    int*   counts  = (int*)alloc((size_t)N * 4);
    int*   row_ptr = (int*)alloc(((size_t)N + 1) * 4);
    int*   cursor  = (int*)alloc((size_t)N * 4);
    int*   csr_src = (int*)alloc((size_t)E * 4);
    int*   bsums   = (int*)alloc(512 * 4);
    int*   boffs   = (int*)alloc(512 * 4);
    float* dinv    = (float*)alloc((size_t)N * 4);
    float* gmax    = (float*)alloc((size_t)B * D * 4);
    float* gsum    = (float*)alloc((size_t)B * D * 4);
    int*   gcnt    = (int*)alloc((size_t)B * 4);

    hipMemsetAsync(counts, 0, (size_t)N * 4, stream);
    hipMemsetAsync(gmax, 0, (size_t)B * D * 4, stream);
    hipMemsetAsync(gsum, 0, (size_t)B * D * 4, stream);
    hipMemsetAsync(gcnt, 0, (size_t)B * 4, stream);

    const int nb = (N + 255) / 256;
    k_count<<<(E + 255) / 256, 256, 0, stream>>>(dst, counts, E);
    k_dinv<<<nb, 256, 0, stream>>>(counts, dinv, N);
    k_gcnt<<<nb, 256, 0, stream>>>(batch, gcnt, N);
    k_scan1<<<nb, 256, 0, stream>>>(counts, row_ptr, bsums, N);
    k_scan2<<<1, 512, 0, stream>>>(bsums, boffs, nb);
    k_scan3<<<nb, 256, 0, stream>>>(row_ptr, cursor, boffs, N, E);
    k_fill<<<(E + 255) / 256, 256, 0, stream>>>(src, dst, cursor, csr_src, E);
    k_cvt_x<<<((N * D / 4) + 255) / 256, 256, 0, stream>>>(x, dinv, hb, N * D / 4);
    k_cvt_w<<<((L * D * D) + 255) / 256, 256, 0, stream>>>(convw, Wt, L * D * D);

    const int ablocks = (N + 3) / 4;
    const int gblocks = (N + 127) / 128;
    for (int l = 0; l < L; l++) {
        k_aggregate<<<ablocks, 256, 0, stream>>>(hb, row_ptr, csr_src, dinv, gbuf, N);
        k_gemm<<<gblocks, 256, 0, stream>>>(gbuf, Wt + l * D * D, convb + (size_t)l * D,
                                            dinv, hb, batch, gmax, gsum, N,
                                            (l == L - 1) ? 1 : 0);
    }
    k_final<<<B, 64, 0, stream>>>(gmax, gsum, gcnt, outw, outb, out);
}

// Round 3
// 782.529 us; speedup vs baseline: 1.3701x; 1.2977x over previous
//
#include <hip/hip_runtime.h>
#include <hip/hip_bf16.h>

#define D 128

typedef __attribute__((ext_vector_type(8))) __bf16 bf16x8;
typedef __attribute__((ext_vector_type(4))) float f32x4;
typedef __attribute__((ext_vector_type(4))) short s16x4;
typedef __attribute__((ext_vector_type(8))) short s16x8;

static __device__ __forceinline__ short f2bf(float f) {
    union { float f; unsigned u; } in; in.f = f;
    unsigned u = in.u;
    u += 0x7fffu + ((u >> 16) & 1u);   // round-to-nearest-even
    return (short)(u >> 16);
}

// ---- degree histogram over dst ----
__global__ void k_count(const int* __restrict__ dst, int* __restrict__ counts, int E) {
    int i = blockIdx.x * blockDim.x + threadIdx.x;
    if (i < E) atomicAdd(&counts[dst[i]], 1);
}

// ---- dinv = rsqrt(indeg + 1) ----
__global__ void k_dinv(const int* __restrict__ counts, float* __restrict__ dinv, int N) {
    int i = blockIdx.x * blockDim.x + threadIdx.x;
    if (i < N) dinv[i] = rsqrtf((float)counts[i] + 1.0f);
}

// ---- graph node counts (for mean pooling + segment offsets) ----
__global__ void k_gcnt(const int* __restrict__ batch, int* __restrict__ gcnt, int N) {
    int i = blockIdx.x * blockDim.x + threadIdx.x;
    if (i < N) atomicAdd(&gcnt[batch[i]], 1);
}

// ---- exclusive scan of gcnt -> gstart (B <= 256, single block) ----
__global__ void k_gscan(const int* __restrict__ gcnt, int* __restrict__ gstart, int B) {
    __shared__ int s[256];
    int t = threadIdx.x;
    int v = (t < B) ? gcnt[t] : 0;
    s[t] = v;
    __syncthreads();
    for (int off = 1; off < 256; off <<= 1) {
        int x = (t >= off) ? s[t - off] : 0;
        __syncthreads();
        s[t] += x;
        __syncthreads();
    }
    if (t < B) gstart[t] = s[t] - v;
}

// ---- 3-kernel exclusive scan of counts -> row_ptr ----
__global__ void k_scan1(const int* __restrict__ counts, int* __restrict__ excl,
                        int* __restrict__ bsums, int N) {
    __shared__ int s[256];
    int i = blockIdx.x * 256 + threadIdx.x;
    int v = (i < N) ? counts[i] : 0;
    s[threadIdx.x] = v;
    __syncthreads();
    for (int off = 1; off < 256; off <<= 1) {
        int t = (threadIdx.x >= off) ? s[threadIdx.x - off] : 0;
        __syncthreads();
        s[threadIdx.x] += t;
        __syncthreads();
    }
    if (i < N) excl[i] = s[threadIdx.x] - v;
    if (threadIdx.x == 255) bsums[blockIdx.x] = s[255];
}

__global__ void k_scan2(const int* __restrict__ bsums, int* __restrict__ boffs, int nb) {
    __shared__ int s[512];
    int t = threadIdx.x;
    int v = (t < nb) ? bsums[t] : 0;
    s[t] = v;
    __syncthreads();
    for (int off = 1; off < 512; off <<= 1) {
        int x = (t >= off) ? s[t - off] : 0;
        __syncthreads();
        s[t] += x;
        __syncthreads();
    }
    if (t < nb) boffs[t] = s[t] - v;
}

__global__ void k_scan3(int* __restrict__ row_ptr, int* __restrict__ cursor,
                        const int* __restrict__ boffs, int N, int E) {
    int i = blockIdx.x * 256 + threadIdx.x;
    if (i < N) {
        int r = row_ptr[i] + boffs[blockIdx.x];
        row_ptr[i] = r;
        cursor[i] = r;
    }
    if (i == 0) row_ptr[N] = E;
}

// ---- scatter edges into CSR slots ----
__global__ void k_fill(const int* __restrict__ src, const int* __restrict__ dst,
                       int* __restrict__ cursor, int* __restrict__ csr_src, int E) {
    int i = blockIdx.x * blockDim.x + threadIdx.x;
    if (i < E) {
        int slot = atomicAdd(&cursor[dst[i]], 1);
        csr_src[slot] = src[i];
    }
}

// ---- x' = dinv[i] * x  -> bf16 (pre-scaled feature rows) ----
__global__ void k_cvt_x(const float* __restrict__ x, const float* __restrict__ dinv,
                        short* __restrict__ xb, int total4) {
    int i = blockIdx.x * blockDim.x + threadIdx.x;
    if (i < total4) {
        float d = dinv[i >> 5];              // D/4 = 32 float4 per row
        float4 v = ((const float4*)x)[i];
        s16x4 o;
        o.x = f2bf(v.x * d); o.y = f2bf(v.y * d);
        o.z = f2bf(v.z * d); o.w = f2bf(v.w * d);
        ((s16x4*)xb)[i] = o;
    }
}

// ---- conv_w: fp32 [L][k][n] -> bf16 transposed [L][n][k] ----
__global__ void k_cvt_w(const float* __restrict__ W, short* __restrict__ Wt, int total) {
    int i = blockIdx.x * blockDim.x + threadIdx.x;
    if (i < total) {
        int l = i >> 14;
        int rem = i & 16383;
        int n = rem >> 7;
        int k = rem & 127;
        Wt[i] = f2bf(W[(l << 14) + (k << 7) + n]);
    }
}

// ---- pull-aggregation on bf16 rows: g[i] = dinv[i] * (h'[i] + sum_edges h'[src]) ----
// One wave per node; 4 groups of 16 lanes each run 4 independent chains
// (16 edges in flight per wave) for latency hiding.
__global__ __launch_bounds__(256) void k_aggregate(
    const short* __restrict__ hb, const int* __restrict__ row_ptr,
    const int* __restrict__ csr_src, const float* __restrict__ dinv,
    short* __restrict__ g, int N)
{
    const int w = threadIdx.x >> 6;
    const int lane = threadIdx.x & 63;
    const int i = blockIdx.x * 4 + w;
    if (i >= N) return;
    const int group = lane >> 4;
    const int off = (lane & 15) * 8;

    float a0[8], a1[8], a2[8], a3[8];
    #pragma unroll
    for (int k = 0; k < 8; k++) { a0[k] = 0.f; a1[k] = 0.f; a2[k] = 0.f; a3[k] = 0.f; }

    const float di = dinv[i];
    const int start = row_ptr[i], end = row_ptr[i + 1];

    if (group == 0) {  // self-loop term
        bf16x8 v = *(const bf16x8*)(hb + (size_t)i * D + off);
        #pragma unroll
        for (int k = 0; k < 8; k++) a0[k] += (float)v[k];
    }

    int e = start + group;
    int s0 = (e      < end) ? csr_src[e]      : -1;
    int s1 = (e + 4  < end) ? csr_src[e + 4]  : -1;
    int s2 = (e + 8  < end) ? csr_src[e + 8]  : -1;
    int s3 = (e + 12 < end) ? csr_src[e + 12] : -1;
    while (s3 >= 0) {
        bf16x8 v0 = *(const bf16x8*)(hb + (size_t)s0 * D + off);
        bf16x8 v1 = *(const bf16x8*)(hb + (size_t)s1 * D + off);
        bf16x8 v2 = *(const bf16x8*)(hb + (size_t)s2 * D + off);
        bf16x8 v3 = *(const bf16x8*)(hb + (size_t)s3 * D + off);
        e += 16;
        s0 = (e      < end) ? csr_src[e]      : -1;
        s1 = (e + 4  < end) ? csr_src[e + 4]  : -1;
        s2 = (e + 8  < end) ? csr_src[e + 8]  : -1;
        s3 = (e + 12 < end) ? csr_src[e + 12] : -1;
        #pragma unroll
        for (int k = 0; k < 8; k++) {
            a0[k] += (float)v0[k]; a1[k] += (float)v1[k];
            a2[k] += (float)v2[k]; a3[k] += (float)v3[k];
        }
    }
    if (s0 >= 0) {
        bf16x8 v = *(const bf16x8*)(hb + (size_t)s0 * D + off);
        #pragma unroll
        for (int k = 0; k < 8; k++) a0[k] += (float)v[k];
    }
    if (s1 >= 0) {
        bf16x8 v = *(const bf16x8*)(hb + (size_t)s1 * D + off);
        #pragma unroll
        for (int k = 0; k < 8; k++) a1[k] += (float)v[k];
    }
    if (s2 >= 0) {
        bf16x8 v = *(const bf16x8*)(hb + (size_t)s2 * D + off);
        #pragma unroll
        for (int k = 0; k < 8; k++) a2[k] += (float)v[k];
    }

    // merge chains + cross-group reduction (lanes {l, l^16, l^32, l^48})
    #pragma unroll
    for (int k = 0; k < 8; k++) {
        float t = (a0[k] + a1[k]) + (a2[k] + a3[k]);
        t += __shfl_xor(t, 16, 64);
        t += __shfl_xor(t, 32, 64);
        a0[k] = t * di;
    }
    if (group == 0) {
        s16x8 o;
        #pragma unroll
        for (int k = 0; k < 8; k++) o[k] = f2bf(a0[k]);
        *(s16x8*)(g + (size_t)i * D + off) = o;
    }
}

// ---- bf16 MFMA GEMM: C = A[N x 128] * W, fused epilogue.
// mode 0: hb_out[r] = bf16( relu(C + b) * dinv[r] )   (pre-scaled next-layer rows)
// mode 1: hrelu[r]  = fp32 relu(C + b)                (pooling input)
__global__ __launch_bounds__(256) void k_gemm(const short* __restrict__ A,
                                              const short* __restrict__ Wt,
                                              const float* __restrict__ bias,
                                              const float* __restrict__ dinv,
                                              short* __restrict__ hb_out,
                                              float* __restrict__ hrelu,
                                              int N, int mode) {
    const int wave = threadIdx.x >> 6;
    const int lane = threadIdx.x & 63;
    const int m_base = blockIdx.x * 128 + wave * 32;
    const int lr = lane & 15;
    const int lq = lane >> 4;

    bf16x8 afrag[2][4];
    #pragma unroll
    for (int rt = 0; rt < 2; rt++) {
        int m = m_base + rt * 16 + lr;
        if (m >= N) m = N - 1;
        const short* ap = A + (size_t)m * D + lq * 8;
        #pragma unroll
        for (int kt = 0; kt < 4; kt++)
            afrag[rt][kt] = *(const bf16x8*)(ap + kt * 32);
    }

    f32x4 acc[2][8];
    #pragma unroll
    for (int rt = 0; rt < 2; rt++)
        #pragma unroll
        for (int nt = 0; nt < 8; nt++) {
            f32x4 z = {0.f, 0.f, 0.f, 0.f};
            acc[rt][nt] = z;
        }

    const short* bp = Wt + lr * D + lq * 8;
    #pragma unroll
    for (int nt = 0; nt < 8; nt++) {
        #pragma unroll
        for (int kt = 0; kt < 4; kt++) {
            bf16x8 b = *(const bf16x8*)(bp + nt * 16 * D + kt * 32);
            acc[0][nt] = __builtin_amdgcn_mfma_f32_16x16x32_bf16(afrag[0][kt], b, acc[0][nt], 0, 0, 0);
            acc[1][nt] = __builtin_amdgcn_mfma_f32_16x16x32_bf16(afrag[1][kt], b, acc[1][nt], 0, 0, 0);
        }
    }

    // C/D layout: col = lane&15, row = (lane>>4)*4 + reg
    float bcol[8];
    #pragma unroll
    for (int nt = 0; nt < 8; nt++) bcol[nt] = bias[nt * 16 + lr];

    #pragma unroll
    for (int rt = 0; rt < 2; rt++) {
        int row0 = m_base + rt * 16 + lq * 4;
        #pragma unroll
        for (int i2 = 0; i2 < 4; i2++) {
            int r = row0 + i2;
            if (r < N) {
                if (mode == 0) {
                    float dr = dinv[r];
                    #pragma unroll
                    for (int nt = 0; nt < 8; nt++) {
                        int col = nt * 16 + lr;
                        float val = fmaxf(acc[rt][nt][i2] + bcol[nt], 0.0f);
                        hb_out[(size_t)r * D + col] = f2bf(val * dr);
                    }
                } else {
                    #pragma unroll
                    for (int nt = 0; nt < 8; nt++) {
                        int col = nt * 16 + lr;
                        hrelu[(size_t)r * D + col] = fmaxf(acc[rt][nt][i2] + bcol[nt], 0.0f);
                    }
                }
            }
        }
    }
}

// ---- segmented pooling: batch is sorted, so graph g owns rows [gstart, gstart+cnt) ----
__global__ __launch_bounds__(256) void k_pool(const float* __restrict__ hrelu,
                                              const int* __restrict__ gstart,
                                              const int* __restrict__ gcnt,
                                              float* __restrict__ gmax,
                                              float* __restrict__ gsum) {
    int g = blockIdx.x;
    int c = threadIdx.x & 127;
    int p = threadIdx.x >> 7;          // 2 row-parities x 128 cols
    int start = gstart[g];
    int endr = start + gcnt[g];

    float mx0 = 0.f, mx1 = 0.f, sm0 = 0.f, sm1 = 0.f;
    int r = start + p;
    for (; r + 2 < endr; r += 4) {
        float v0 = hrelu[(size_t)r * D + c];
        float v1 = hrelu[(size_t)(r + 2) * D + c];
        mx0 = fmaxf(mx0, v0); sm0 += v0;
        mx1 = fmaxf(mx1, v1); sm1 += v1;
    }
    if (r < endr) {
        float v0 = hrelu[(size_t)r * D + c];
        mx0 = fmaxf(mx0, v0); sm0 += v0;
    }
    float mx = fmaxf(mx0, mx1), sm = sm0 + sm1;

    __shared__ float smx[128], ssm[128];
    if (p == 1) { smx[c] = mx; ssm[c] = sm; }
    __syncthreads();
    if (p == 0) {
        gmax[g * D + c] = fmaxf(mx, smx[c]);
        gsum[g * D + c] = sm + ssm[c];
    }
}

// ---- final: out[g] = [gmax, gsum/cnt, gsum] @ out_w + out_b ----
__global__ void k_final(const float* __restrict__ gmax, const float* __restrict__ gsum,
                        const int* __restrict__ gcnt, const float* __restrict__ ow,
                        const float* __restrict__ ob, float* __restrict__ out) {
    int g = blockIdx.x;
    int t = threadIdx.x;  // 64
    float part[10];
    #pragma unroll
    for (int o = 0; o < 10; o++) part[o] = 0.f;
    float invc = 1.0f / fmaxf((float)gcnt[g], 1.0f);
    for (int k = t; k < 3 * D; k += 64) {
        float pk;
        if (k < D) pk = gmax[g * D + k];
        else if (k < 2 * D) pk = gsum[g * D + (k - D)] * invc;
        else pk = gsum[g * D + (k - 2 * D)];
        const float* w = ow + k * 10;
        #pragma unroll
        for (int o = 0; o < 10; o++) part[o] += pk * w[o];
    }
    #pragma unroll
    for (int off = 32; off > 0; off >>= 1)
        #pragma unroll
        for (int o = 0; o < 10; o++) part[o] += __shfl_down(part[o], off, 64);
    if (t == 0)
        #pragma unroll
        for (int o = 0; o < 10; o++) out[g * 10 + o] = part[o] + ob[o];
}

extern "C" void kernel_launch(void* const* d_in, const int* in_sizes, int n_in,
                              void* d_out, int out_size, void* d_ws, size_t ws_size,
                              hipStream_t stream) {
    const float* x     = (const float*)d_in[0];
    const int*   ei    = (const int*)d_in[1];
    const int*   batch = (const int*)d_in[2];
    const float* convw = (const float*)d_in[3];
    const float* convb = (const float*)d_in[4];
    const float* outw  = (const float*)d_in[5];
    const float* outb  = (const float*)d_in[6];
    float* out = (float*)d_out;

    const int N = in_sizes[0] / D;        // 100000
    const int E = in_sizes[1] / 2;        // 1600000
    const int L = in_sizes[3] / (D * D);  // 3
    const int B = out_size / 10;          // 256

    const int* src = ei;
    const int* dst = ei + E;

    char* p = (char*)d_ws;
    auto alloc = [&](size_t bytes) { char* r = p; p += (bytes + 255) & ~255ull; return r; };
    short* hb      = (short*)alloc((size_t)N * D * 2);      // bf16 pre-scaled feature rows
    short* gbuf    = (short*)alloc((size_t)N * D * 2);      // bf16 aggregated rows (GEMM input)
    float* hrelu   = (float*)alloc((size_t)N * D * 4);      // fp32 last-layer relu (pooling input)
    short* Wt      = (short*)alloc((size_t)L * D * D * 2);  // bf16 W^T
    int*   counts  = (int*)alloc((size_t)N * 4);
    int*   row_ptr = (int*)alloc(((size_t)N + 1) * 4);
    int*   cursor  = (int*)alloc((size_t)N * 4);
    int*   csr_src = (int*)alloc((size_t)E * 4);
    int*   bsums   = (int*)alloc(512 * 4);
    int*   boffs   = (int*)alloc(512 * 4);
    float* dinv    = (float*)alloc((size_t)N * 4);
    float* gmax    = (float*)alloc((size_t)B * D * 4);
    float* gsum    = (float*)alloc((size_t)B * D * 4);
    int*   gcnt    = (int*)alloc((size_t)B * 4);
    int*   gstart  = (int*)alloc((size_t)B * 4);

    hipMemsetAsync(counts, 0, (size_t)N * 4, stream);
    hipMemsetAsync(gcnt, 0, (size_t)B * 4, stream);

    const int nb = (N + 255) / 256;
    k_count<<<(E + 255) / 256, 256, 0, stream>>>(dst, counts, E);
    k_dinv<<<nb, 256, 0, stream>>>(counts, dinv, N);
    k_gcnt<<<nb, 256, 0, stream>>>(batch, gcnt, N);
    k_gscan<<<1, 256, 0, stream>>>(gcnt, gstart, B);
    k_scan1<<<nb, 256, 0, stream>>>(counts, row_ptr, bsums, N);
    k_scan2<<<1, 512, 0, stream>>>(bsums, boffs, nb);
    k_scan3<<<nb, 256, 0, stream>>>(row_ptr, cursor, boffs, N, E);
    k_fill<<<(E + 255) / 256, 256, 0, stream>>>(src, dst, cursor, csr_src, E);
    k_cvt_x<<<((N * D / 4) + 255) / 256, 256, 0, stream>>>(x, dinv, hb, N * D / 4);
    k_cvt_w<<<((L * D * D) + 255) / 256, 256, 0, stream>>>(convw, Wt, L * D * D);

    const int ablocks = (N + 3) / 4;
    const int gblocks = (N + 127) / 128;
    for (int l = 0; l < L; l++) {
        k_aggregate<<<ablocks, 256, 0, stream>>>(hb, row_ptr, csr_src, dinv, gbuf, N);
        k_gemm<<<gblocks, 256, 0, stream>>>(gbuf, Wt + l * D * D, convb + (size_t)l * D,
                                            dinv, hb, hrelu, N, (l == L - 1) ? 1 : 0);
    }
    k_pool<<<B, 256, 0, stream>>>(hrelu, gstart, gcnt, gmax, gsum);
    k_final<<<B, 64, 0, stream>>>(gmax, gsum, gcnt, outw, outb, out);
}

// Round 4
// 632.056 us; speedup vs baseline: 1.6963x; 1.2381x over previous
//
#include <hip/hip_runtime.h>
#include <hip/hip_bf16.h>

#define D 128

typedef __attribute__((ext_vector_type(8))) __bf16 bf16x8;
typedef __attribute__((ext_vector_type(4))) float f32x4;
typedef __attribute__((ext_vector_type(4))) short s16x4;
typedef __attribute__((ext_vector_type(8))) short s16x8;

static __device__ __forceinline__ short f2bf(float f) {
    union { float f; unsigned u; } in; in.f = f;
    unsigned u = in.u;
    u += 0x7fffu + ((u >> 16) & 1u);   // round-to-nearest-even
    return (short)(u >> 16);
}

// ---- degree histogram over dst ----
__global__ void k_count(const int* __restrict__ dst, int* __restrict__ counts, int E) {
    int i = blockIdx.x * blockDim.x + threadIdx.x;
    if (i < E) atomicAdd(&counts[dst[i]], 1);
}

// ---- dinv = rsqrt(indeg + 1) ----
__global__ void k_dinv(const int* __restrict__ counts, float* __restrict__ dinv, int N) {
    int i = blockIdx.x * blockDim.x + threadIdx.x;
    if (i < N) dinv[i] = rsqrtf((float)counts[i] + 1.0f);
}

// ---- batch is SORTED: graph segment boundaries via binary search (no atomics) ----
__global__ void k_gseg(const int* __restrict__ batch, int* __restrict__ gstart,
                       int N, int B) {
    int g = blockIdx.x * blockDim.x + threadIdx.x;
    if (g > B) return;
    int lo = 0, hi = N;
    while (lo < hi) {                    // lower_bound: first i with batch[i] >= g
        int mid = (lo + hi) >> 1;
        if (batch[mid] < g) lo = mid + 1; else hi = mid;
    }
    gstart[g] = lo;
}

__global__ void k_gcnt_seg(const int* __restrict__ gstart, int* __restrict__ gcnt, int B) {
    int g = blockIdx.x * blockDim.x + threadIdx.x;
    if (g < B) gcnt[g] = gstart[g + 1] - gstart[g];
}

// ---- 3-kernel exclusive scan of counts -> row_ptr ----
__global__ void k_scan1(const int* __restrict__ counts, int* __restrict__ excl,
                        int* __restrict__ bsums, int N) {
    __shared__ int s[256];
    int i = blockIdx.x * 256 + threadIdx.x;
    int v = (i < N) ? counts[i] : 0;
    s[threadIdx.x] = v;
    __syncthreads();
    for (int off = 1; off < 256; off <<= 1) {
        int t = (threadIdx.x >= off) ? s[threadIdx.x - off] : 0;
        __syncthreads();
        s[threadIdx.x] += t;
        __syncthreads();
    }
    if (i < N) excl[i] = s[threadIdx.x] - v;
    if (threadIdx.x == 255) bsums[blockIdx.x] = s[255];
}

__global__ void k_scan2(const int* __restrict__ bsums, int* __restrict__ boffs, int nb) {
    __shared__ int s[512];
    int t = threadIdx.x;
    int v = (t < nb) ? bsums[t] : 0;
    s[t] = v;
    __syncthreads();
    for (int off = 1; off < 512; off <<= 1) {
        int x = (t >= off) ? s[t - off] : 0;
        __syncthreads();
        s[t] += x;
        __syncthreads();
    }
    if (t < nb) boffs[t] = s[t] - v;
}

__global__ void k_scan3(int* __restrict__ row_ptr, int* __restrict__ cursor,
                        const int* __restrict__ boffs, int N, int E) {
    int i = blockIdx.x * 256 + threadIdx.x;
    if (i < N) {
        int r = row_ptr[i] + boffs[blockIdx.x];
        row_ptr[i] = r;
        cursor[i] = r;
    }
    if (i == 0) row_ptr[N] = E;
}

// ---- scatter edges into CSR slots ----
__global__ void k_fill(const int* __restrict__ src, const int* __restrict__ dst,
                       int* __restrict__ cursor, int* __restrict__ csr_src, int E) {
    int i = blockIdx.x * blockDim.x + threadIdx.x;
    if (i < E) {
        int slot = atomicAdd(&cursor[dst[i]], 1);
        csr_src[slot] = src[i];
    }
}

// ---- x' = dinv[i] * x  -> bf16 (pre-scaled feature rows) ----
__global__ void k_cvt_x(const float* __restrict__ x, const float* __restrict__ dinv,
                        short* __restrict__ xb, int total4) {
    int i = blockIdx.x * blockDim.x + threadIdx.x;
    if (i < total4) {
        float d = dinv[i >> 5];              // D/4 = 32 float4 per row
        float4 v = ((const float4*)x)[i];
        s16x4 o;
        o.x = f2bf(v.x * d); o.y = f2bf(v.y * d);
        o.z = f2bf(v.z * d); o.w = f2bf(v.w * d);
        ((s16x4*)xb)[i] = o;
    }
}

// ---- conv_w: fp32 [L][k][n] -> bf16 transposed [L][n][k] ----
__global__ void k_cvt_w(const float* __restrict__ W, short* __restrict__ Wt, int total) {
    int i = blockIdx.x * blockDim.x + threadIdx.x;
    if (i < total) {
        int l = i >> 14;
        int rem = i & 16383;
        int n = rem >> 7;
        int k = rem & 127;
        Wt[i] = f2bf(W[(l << 14) + (k << 7) + n]);
    }
}

// ---- pull-aggregation on bf16 rows: g[i] = dinv[i] * (h'[i] + sum_edges h'[src]) ----
// One wave per node; 4 groups of 16 lanes each run 4 independent chains
// (16 edges in flight per wave) for latency hiding.
__global__ __launch_bounds__(256) void k_aggregate(
    const short* __restrict__ hb, const int* __restrict__ row_ptr,
    const int* __restrict__ csr_src, const float* __restrict__ dinv,
    short* __restrict__ g, int N)
{
    const int w = threadIdx.x >> 6;
    const int lane = threadIdx.x & 63;
    const int i = blockIdx.x * 4 + w;
    if (i >= N) return;
    const int group = lane >> 4;
    const int off = (lane & 15) * 8;

    float a0[8], a1[8], a2[8], a3[8];
    #pragma unroll
    for (int k = 0; k < 8; k++) { a0[k] = 0.f; a1[k] = 0.f; a2[k] = 0.f; a3[k] = 0.f; }

    const float di = dinv[i];
    const int start = row_ptr[i], end = row_ptr[i + 1];

    if (group == 0) {  // self-loop term
        bf16x8 v = *(const bf16x8*)(hb + (size_t)i * D + off);
        #pragma unroll
        for (int k = 0; k < 8; k++) a0[k] += (float)v[k];
    }

    int e = start + group;
    int s0 = (e      < end) ? csr_src[e]      : -1;
    int s1 = (e + 4  < end) ? csr_src[e + 4]  : -1;
    int s2 = (e + 8  < end) ? csr_src[e + 8]  : -1;
    int s3 = (e + 12 < end) ? csr_src[e + 12] : -1;
    while (s3 >= 0) {
        bf16x8 v0 = *(const bf16x8*)(hb + (size_t)s0 * D + off);
        bf16x8 v1 = *(const bf16x8*)(hb + (size_t)s1 * D + off);
        bf16x8 v2 = *(const bf16x8*)(hb + (size_t)s2 * D + off);
        bf16x8 v3 = *(const bf16x8*)(hb + (size_t)s3 * D + off);
        e += 16;
        s0 = (e      < end) ? csr_src[e]      : -1;
        s1 = (e + 4  < end) ? csr_src[e + 4]  : -1;
        s2 = (e + 8  < end) ? csr_src[e + 8]  : -1;
        s3 = (e + 12 < end) ? csr_src[e + 12] : -1;
        #pragma unroll
        for (int k = 0; k < 8; k++) {
            a0[k] += (float)v0[k]; a1[k] += (float)v1[k];
            a2[k] += (float)v2[k]; a3[k] += (float)v3[k];
        }
    }
    if (s0 >= 0) {
        bf16x8 v = *(const bf16x8*)(hb + (size_t)s0 * D + off);
        #pragma unroll
        for (int k = 0; k < 8; k++) a0[k] += (float)v[k];
    }
    if (s1 >= 0) {
        bf16x8 v = *(const bf16x8*)(hb + (size_t)s1 * D + off);
        #pragma unroll
        for (int k = 0; k < 8; k++) a1[k] += (float)v[k];
    }
    if (s2 >= 0) {
        bf16x8 v = *(const bf16x8*)(hb + (size_t)s2 * D + off);
        #pragma unroll
        for (int k = 0; k < 8; k++) a2[k] += (float)v[k];
    }

    // merge chains + cross-group reduction (lanes {l, l^16, l^32, l^48})
    #pragma unroll
    for (int k = 0; k < 8; k++) {
        float t = (a0[k] + a1[k]) + (a2[k] + a3[k]);
        t += __shfl_xor(t, 16, 64);
        t += __shfl_xor(t, 32, 64);
        a0[k] = t * di;
    }
    if (group == 0) {
        s16x8 o;
        #pragma unroll
        for (int k = 0; k < 8; k++) o[k] = f2bf(a0[k]);
        *(s16x8*)(g + (size_t)i * D + off) = o;
    }
}

// ---- bf16 MFMA GEMM: C = A[N x 128] * W, fused epilogue.
// mode 0: hb_out[r] = bf16( relu(C + b) * dinv[r] )   (pre-scaled next-layer rows)
// mode 1: hrelu[r]  = fp32 relu(C + b)                (pooling input)
__global__ __launch_bounds__(256) void k_gemm(const short* __restrict__ A,
                                              const short* __restrict__ Wt,
                                              const float* __restrict__ bias,
                                              const float* __restrict__ dinv,
                                              short* __restrict__ hb_out,
                                              float* __restrict__ hrelu,
                                              int N, int mode) {
    const int wave = threadIdx.x >> 6;
    const int lane = threadIdx.x & 63;
    const int m_base = blockIdx.x * 128 + wave * 32;
    const int lr = lane & 15;
    const int lq = lane >> 4;

    bf16x8 afrag[2][4];
    #pragma unroll
    for (int rt = 0; rt < 2; rt++) {
        int m = m_base + rt * 16 + lr;
        if (m >= N) m = N - 1;
        const short* ap = A + (size_t)m * D + lq * 8;
        #pragma unroll
        for (int kt = 0; kt < 4; kt++)
            afrag[rt][kt] = *(const bf16x8*)(ap + kt * 32);
    }

    f32x4 acc[2][8];
    #pragma unroll
    for (int rt = 0; rt < 2; rt++)
        #pragma unroll
        for (int nt = 0; nt < 8; nt++) {
            f32x4 z = {0.f, 0.f, 0.f, 0.f};
            acc[rt][nt] = z;
        }

    const short* bp = Wt + lr * D + lq * 8;
    #pragma unroll
    for (int nt = 0; nt < 8; nt++) {
        #pragma unroll
        for (int kt = 0; kt < 4; kt++) {
            bf16x8 b = *(const bf16x8*)(bp + nt * 16 * D + kt * 32);
            acc[0][nt] = __builtin_amdgcn_mfma_f32_16x16x32_bf16(afrag[0][kt], b, acc[0][nt], 0, 0, 0);
            acc[1][nt] = __builtin_amdgcn_mfma_f32_16x16x32_bf16(afrag[1][kt], b, acc[1][nt], 0, 0, 0);
        }
    }

    // C/D layout: col = lane&15, row = (lane>>4)*4 + reg
    float bcol[8];
    #pragma unroll
    for (int nt = 0; nt < 8; nt++) bcol[nt] = bias[nt * 16 + lr];

    #pragma unroll
    for (int rt = 0; rt < 2; rt++) {
        int row0 = m_base + rt * 16 + lq * 4;
        #pragma unroll
        for (int i2 = 0; i2 < 4; i2++) {
            int r = row0 + i2;
            if (r < N) {
                if (mode == 0) {
                    float dr = dinv[r];
                    #pragma unroll
                    for (int nt = 0; nt < 8; nt++) {
                        int col = nt * 16 + lr;
                        float val = fmaxf(acc[rt][nt][i2] + bcol[nt], 0.0f);
                        hb_out[(size_t)r * D + col] = f2bf(val * dr);
                    }
                } else {
                    #pragma unroll
                    for (int nt = 0; nt < 8; nt++) {
                        int col = nt * 16 + lr;
                        hrelu[(size_t)r * D + col] = fmaxf(acc[rt][nt][i2] + bcol[nt], 0.0f);
                    }
                }
            }
        }
    }
}

// ---- segmented pooling: batch is sorted, so graph g owns rows [gstart, gstart+cnt) ----
__global__ __launch_bounds__(256) void k_pool(const float* __restrict__ hrelu,
                                              const int* __restrict__ gstart,
                                              const int* __restrict__ gcnt,
                                              float* __restrict__ gmax,
                                              float* __restrict__ gsum) {
    int g = blockIdx.x;
    int c = threadIdx.x & 127;
    int p = threadIdx.x >> 7;          // 2 row-parities x 128 cols
    int start = gstart[g];
    int endr = start + gcnt[g];

    float mx0 = 0.f, mx1 = 0.f, sm0 = 0.f, sm1 = 0.f;
    int r = start + p;
    for (; r + 2 < endr; r += 4) {
        float v0 = hrelu[(size_t)r * D + c];
        float v1 = hrelu[(size_t)(r + 2) * D + c];
        mx0 = fmaxf(mx0, v0); sm0 += v0;
        mx1 = fmaxf(mx1, v1); sm1 += v1;
    }
    if (r < endr) {
        float v0 = hrelu[(size_t)r * D + c];
        mx0 = fmaxf(mx0, v0); sm0 += v0;
    }
    float mx = fmaxf(mx0, mx1), sm = sm0 + sm1;

    __shared__ float smx[128], ssm[128];
    if (p == 1) { smx[c] = mx; ssm[c] = sm; }
    __syncthreads();
    if (p == 0) {
        gmax[g * D + c] = fmaxf(mx, smx[c]);
        gsum[g * D + c] = sm + ssm[c];
    }
}

// ---- final: out[g] = [gmax, gsum/cnt, gsum] @ out_w + out_b ----
__global__ void k_final(const float* __restrict__ gmax, const float* __restrict__ gsum,
                        const int* __restrict__ gcnt, const float* __restrict__ ow,
                        const float* __restrict__ ob, float* __restrict__ out) {
    int g = blockIdx.x;
    int t = threadIdx.x;  // 64
    float part[10];
    #pragma unroll
    for (int o = 0; o < 10; o++) part[o] = 0.f;
    float invc = 1.0f / fmaxf((float)gcnt[g], 1.0f);
    for (int k = t; k < 3 * D; k += 64) {
        float pk;
        if (k < D) pk = gmax[g * D + k];
        else if (k < 2 * D) pk = gsum[g * D + (k - D)] * invc;
        else pk = gsum[g * D + (k - 2 * D)];
        const float* w = ow + k * 10;
        #pragma unroll
        for (int o = 0; o < 10; o++) part[o] += pk * w[o];
    }
    #pragma unroll
    for (int off = 32; off > 0; off >>= 1)
        #pragma unroll
        for (int o = 0; o < 10; o++) part[o] += __shfl_down(part[o], off, 64);
    if (t == 0)
        #pragma unroll
        for (int o = 0; o < 10; o++) out[g * 10 + o] = part[o] + ob[o];
}

extern "C" void kernel_launch(void* const* d_in, const int* in_sizes, int n_in,
                              void* d_out, int out_size, void* d_ws, size_t ws_size,
                              hipStream_t stream) {
    const float* x     = (const float*)d_in[0];
    const int*   ei    = (const int*)d_in[1];
    const int*   batch = (const int*)d_in[2];
    const float* convw = (const float*)d_in[3];
    const float* convb = (const float*)d_in[4];
    const float* outw  = (const float*)d_in[5];
    const float* outb  = (const float*)d_in[6];
    float* out = (float*)d_out;

    const int N = in_sizes[0] / D;        // 100000
    const int E = in_sizes[1] / 2;        // 1600000
    const int L = in_sizes[3] / (D * D);  // 3
    const int B = out_size / 10;          // 256

    const int* src = ei;
    const int* dst = ei + E;

    char* p = (char*)d_ws;
    auto alloc = [&](size_t bytes) { char* r = p; p += (bytes + 255) & ~255ull; return r; };
    short* hb      = (short*)alloc((size_t)N * D * 2);      // bf16 pre-scaled feature rows
    short* gbuf    = (short*)alloc((size_t)N * D * 2);      // bf16 aggregated rows (GEMM input)
    float* hrelu   = (float*)alloc((size_t)N * D * 4);      // fp32 last-layer relu (pooling input)
    short* Wt      = (short*)alloc((size_t)L * D * D * 2);  // bf16 W^T
    int*   counts  = (int*)alloc((size_t)N * 4);
    int*   row_ptr = (int*)alloc(((size_t)N + 1) * 4);
    int*   cursor  = (int*)alloc((size_t)N * 4);
    int*   csr_src = (int*)alloc((size_t)E * 4);
    int*   bsums   = (int*)alloc(512 * 4);
    int*   boffs   = (int*)alloc(512 * 4);
    float* dinv    = (float*)alloc((size_t)N * 4);
    float* gmax    = (float*)alloc((size_t)B * D * 4);
    float* gsum    = (float*)alloc((size_t)B * D * 4);
    int*   gcnt    = (int*)alloc((size_t)B * 4);
    int*   gstart  = (int*)alloc(((size_t)B + 1) * 4);

    hipMemsetAsync(counts, 0, (size_t)N * 4, stream);

    const int nb = (N + 255) / 256;
    k_count<<<(E + 255) / 256, 256, 0, stream>>>(dst, counts, E);
    k_dinv<<<nb, 256, 0, stream>>>(counts, dinv, N);
    k_gseg<<<1, 512, 0, stream>>>(batch, gstart, N, B);
    k_gcnt_seg<<<1, 256, 0, stream>>>(gstart, gcnt, B);
    k_scan1<<<nb, 256, 0, stream>>>(counts, row_ptr, bsums, N);
    k_scan2<<<1, 512, 0, stream>>>(bsums, boffs, nb);
    k_scan3<<<nb, 256, 0, stream>>>(row_ptr, cursor, boffs, N, E);
    k_fill<<<(E + 255) / 256, 256, 0, stream>>>(src, dst, cursor, csr_src, E);
    k_cvt_x<<<((N * D / 4) + 255) / 256, 256, 0, stream>>>(x, dinv, hb, N * D / 4);
    k_cvt_w<<<((L * D * D) + 255) / 256, 256, 0, stream>>>(convw, Wt, L * D * D);

    const int ablocks = (N + 3) / 4;
    const int gblocks = (N + 127) / 128;
    for (int l = 0; l < L; l++) {
        k_aggregate<<<ablocks, 256, 0, stream>>>(hb, row_ptr, csr_src, dinv, gbuf, N);
        k_gemm<<<gblocks, 256, 0, stream>>>(gbuf, Wt + l * D * D, convb + (size_t)l * D,
                                            dinv, hb, hrelu, N, (l == L - 1) ? 1 : 0);
    }
    k_pool<<<B, 256, 0, stream>>>(hrelu, gstart, gcnt, gmax, gsum);
    k_final<<<B, 64, 0, stream>>>(gmax, gsum, gcnt, outw, outb, out);
}

// Round 5
// 566.866 us; speedup vs baseline: 1.8914x; 1.1150x over previous
//
#include <hip/hip_runtime.h>
#include <hip/hip_bf16.h>

#define D 128
#define NP 8   // src-range passes / sub-buckets per dst

typedef __attribute__((ext_vector_type(8))) __bf16 bf16x8;
typedef __attribute__((ext_vector_type(4))) float f32x4;
typedef __attribute__((ext_vector_type(4))) short s16x4;
typedef __attribute__((ext_vector_type(8))) short s16x8;

static __device__ __forceinline__ short f2bf(float f) {
    union { float f; unsigned u; } in; in.f = f;
    unsigned u = in.u;
    u += 0x7fffu + ((u >> 16) & 1u);   // round-to-nearest-even
    return (short)(u >> 16);
}

// ---- histogram over key = dst*8 + srcHi, XCD-partitioned by dst range ----
// blockIdx.x % 8 selects a dst partition: each partition's counts region is
// written from (heuristically) one XCD -> dirty L2 lines written back once.
__global__ void k_count(const int* __restrict__ src, const int* __restrict__ dst,
                        int* __restrict__ counts, int E, int dpp, int spp) {
    int part = blockIdx.x & 7;
    int i = (blockIdx.x >> 3) * blockDim.x + threadIdx.x;
    if (i < E) {
        int d = dst[i];
        int lo = part * dpp;
        if (d >= lo && d < lo + dpp) {
            int sh = src[i] / spp; if (sh > NP - 1) sh = NP - 1;
            atomicAdd(&counts[d * NP + sh], 1);
        }
    }
}

// ---- dinv = rsqrt(indeg + 1), indeg from bucketed row_ptr ----
__global__ void k_dinv(const int* __restrict__ row_ptr, float* __restrict__ dinv, int N) {
    int i = blockIdx.x * blockDim.x + threadIdx.x;
    if (i < N) {
        int deg = row_ptr[i * NP + NP] - row_ptr[i * NP];
        dinv[i] = rsqrtf((float)deg + 1.0f);
    }
}

// ---- batch is SORTED: graph segment boundaries via binary search (no atomics) ----
__global__ void k_gseg(const int* __restrict__ batch, int* __restrict__ gstart,
                       int N, int B) {
    int g = blockIdx.x * blockDim.x + threadIdx.x;
    if (g > B) return;
    int lo = 0, hi = N;
    while (lo < hi) {                    // lower_bound: first i with batch[i] >= g
        int mid = (lo + hi) >> 1;
        if (batch[mid] < g) lo = mid + 1; else hi = mid;
    }
    gstart[g] = lo;
}

__global__ void k_gcnt_seg(const int* __restrict__ gstart, int* __restrict__ gcnt, int B) {
    int g = blockIdx.x * blockDim.x + threadIdx.x;
    if (g < B) gcnt[g] = gstart[g + 1] - gstart[g];
}

// ---- generic block-local exclusive scan (256/block) + block sums ----
__global__ void k_scan1(const int* __restrict__ in, int* __restrict__ excl,
                        int* __restrict__ bsums, int len) {
    __shared__ int s[256];
    int i = blockIdx.x * 256 + threadIdx.x;
    int v = (i < len) ? in[i] : 0;
    s[threadIdx.x] = v;
    __syncthreads();
    for (int off = 1; off < 256; off <<= 1) {
        int t = (threadIdx.x >= off) ? s[threadIdx.x - off] : 0;
        __syncthreads();
        s[threadIdx.x] += t;
        __syncthreads();
    }
    if (i < len) excl[i] = s[threadIdx.x] - v;
    if (threadIdx.x == 255) bsums[blockIdx.x] = s[255];
}

__global__ void k_scan2(const int* __restrict__ bsums, int* __restrict__ boffs, int nb) {
    __shared__ int s[512];
    int t = threadIdx.x;
    int v = (t < nb) ? bsums[t] : 0;
    s[t] = v;
    __syncthreads();
    for (int off = 1; off < 512; off <<= 1) {
        int x = (t >= off) ? s[t - off] : 0;
        __syncthreads();
        s[t] += x;
        __syncthreads();
    }
    if (t < nb) boffs[t] = s[t] - v;
}

// excl1[i] += boffs2[blockIdx.x]   (level-1 fixup)
__global__ void k_scan_add(int* __restrict__ excl1, const int* __restrict__ boffs2, int len) {
    int i = blockIdx.x * 256 + threadIdx.x;
    if (i < len) excl1[i] += boffs2[blockIdx.x];
}

// level-0 fixup + cursor copy + sentinel
__global__ void k_scan3(int* __restrict__ row_ptr, int* __restrict__ cursor,
                        const int* __restrict__ boffs, int len, int E) {
    int i = blockIdx.x * 256 + threadIdx.x;
    if (i < len) {
        int r = row_ptr[i] + boffs[blockIdx.x];
        row_ptr[i] = r;
        cursor[i] = r;
    }
    if (i == 0) row_ptr[len] = E;
}

// ---- scatter edges into CSR slots (key = dst*8+srcHi), XCD-partitioned by dst ----
__global__ void k_fill(const int* __restrict__ src, const int* __restrict__ dst,
                       int* __restrict__ cursor, int* __restrict__ csr_src,
                       int E, int dpp, int spp) {
    int part = blockIdx.x & 7;
    int i = (blockIdx.x >> 3) * blockDim.x + threadIdx.x;
    if (i < E) {
        int d = dst[i];
        int lo = part * dpp;
        if (d >= lo && d < lo + dpp) {
            int s = src[i];
            int sh = s / spp; if (sh > NP - 1) sh = NP - 1;
            int slot = atomicAdd(&cursor[d * NP + sh], 1);
            csr_src[slot] = s;
        }
    }
}

// ---- x' = dinv[i] * x  -> bf16 (pre-scaled feature rows) ----
__global__ void k_cvt_x(const float* __restrict__ x, const float* __restrict__ dinv,
                        short* __restrict__ xb, int total4) {
    int i = blockIdx.x * blockDim.x + threadIdx.x;
    if (i < total4) {
        float d = dinv[i >> 5];              // D/4 = 32 float4 per row
        float4 v = ((const float4*)x)[i];
        s16x4 o;
        o.x = f2bf(v.x * d); o.y = f2bf(v.y * d);
        o.z = f2bf(v.z * d); o.w = f2bf(v.w * d);
        ((s16x4*)xb)[i] = o;
    }
}

// ---- conv_w: fp32 [L][k][n] -> bf16 transposed [L][n][k] ----
__global__ void k_cvt_w(const float* __restrict__ W, short* __restrict__ Wt, int total) {
    int i = blockIdx.x * blockDim.x + threadIdx.x;
    if (i < total) {
        int l = i >> 14;
        int rem = i & 16383;
        int n = rem >> 7;
        int k = rem & 127;
        Wt[i] = f2bf(W[(l << 14) + (k << 7) + n]);
    }
}

// ---- pull-aggregation, src-range pass loop for L2 locality ----
// One 16-lane group owns one node (full 128-col row, 8 bf16/lane).
// Pass p gathers only rows in src-range p (~3.2 MB -> replicated in XCD L2s).
__global__ __launch_bounds__(256) void k_aggregate(
    const short* __restrict__ hb, const int* __restrict__ row_ptr,
    const int* __restrict__ csr_src, const float* __restrict__ dinv,
    short* __restrict__ g, int N)
{
    const int wave = threadIdx.x >> 6;
    const int lane = threadIdx.x & 63;
    const int group = lane >> 4;
    const int off = (lane & 15) * 8;
    const int i = blockIdx.x * 16 + wave * 4 + group;
    if (i >= N) return;   // no barriers below: early-out is safe

    float acc[8];
    {   // self-loop term
        bf16x8 v = *(const bf16x8*)(hb + (size_t)i * D + off);
        #pragma unroll
        for (int k = 0; k < 8; k++) acc[k] = (float)v[k];
    }

    const int kb = i * NP;
    int s = row_ptr[kb];
    #pragma unroll 1
    for (int p = 0; p < NP; p++) {
        int e = row_ptr[kb + p + 1];
        for (int t = s; t < e; t += 4) {   // 4-deep chained loads
            int i0 = csr_src[t];
            int i1 = (t + 1 < e) ? csr_src[t + 1] : -1;
            int i2 = (t + 2 < e) ? csr_src[t + 2] : -1;
            int i3 = (t + 3 < e) ? csr_src[t + 3] : -1;
            bf16x8 v0 = *(const bf16x8*)(hb + (size_t)i0 * D + off);
            bf16x8 v1, v2, v3;
            if (i1 >= 0) v1 = *(const bf16x8*)(hb + (size_t)i1 * D + off);
            if (i2 >= 0) v2 = *(const bf16x8*)(hb + (size_t)i2 * D + off);
            if (i3 >= 0) v3 = *(const bf16x8*)(hb + (size_t)i3 * D + off);
            #pragma unroll
            for (int k = 0; k < 8; k++) acc[k] += (float)v0[k];
            if (i1 >= 0) {
                #pragma unroll
                for (int k = 0; k < 8; k++) acc[k] += (float)v1[k];
            }
            if (i2 >= 0) {
                #pragma unroll
                for (int k = 0; k < 8; k++) acc[k] += (float)v2[k];
            }
            if (i3 >= 0) {
                #pragma unroll
                for (int k = 0; k < 8; k++) acc[k] += (float)v3[k];
            }
        }
        s = e;
    }

    const float di = dinv[i];
    s16x8 o;
    #pragma unroll
    for (int k = 0; k < 8; k++) o[k] = f2bf(acc[k] * di);
    *(s16x8*)(g + (size_t)i * D + off) = o;
}

// ---- bf16 MFMA GEMM: C = A[N x 128] * W, fused epilogue.
// mode 0: hb_out[r] = bf16( relu(C + b) * dinv[r] )   (pre-scaled next-layer rows)
// mode 1: hrelu[r]  = fp32 relu(C + b)                (pooling input)
__global__ __launch_bounds__(256) void k_gemm(const short* __restrict__ A,
                                              const short* __restrict__ Wt,
                                              const float* __restrict__ bias,
                                              const float* __restrict__ dinv,
                                              short* __restrict__ hb_out,
                                              float* __restrict__ hrelu,
                                              int N, int mode) {
    const int wave = threadIdx.x >> 6;
    const int lane = threadIdx.x & 63;
    const int m_base = blockIdx.x * 128 + wave * 32;
    const int lr = lane & 15;
    const int lq = lane >> 4;

    bf16x8 afrag[2][4];
    #pragma unroll
    for (int rt = 0; rt < 2; rt++) {
        int m = m_base + rt * 16 + lr;
        if (m >= N) m = N - 1;
        const short* ap = A + (size_t)m * D + lq * 8;
        #pragma unroll
        for (int kt = 0; kt < 4; kt++)
            afrag[rt][kt] = *(const bf16x8*)(ap + kt * 32);
    }

    f32x4 acc[2][8];
    #pragma unroll
    for (int rt = 0; rt < 2; rt++)
        #pragma unroll
        for (int nt = 0; nt < 8; nt++) {
            f32x4 z = {0.f, 0.f, 0.f, 0.f};
            acc[rt][nt] = z;
        }

    const short* bp = Wt + lr * D + lq * 8;
    #pragma unroll
    for (int nt = 0; nt < 8; nt++) {
        #pragma unroll
        for (int kt = 0; kt < 4; kt++) {
            bf16x8 b = *(const bf16x8*)(bp + nt * 16 * D + kt * 32);
            acc[0][nt] = __builtin_amdgcn_mfma_f32_16x16x32_bf16(afrag[0][kt], b, acc[0][nt], 0, 0, 0);
            acc[1][nt] = __builtin_amdgcn_mfma_f32_16x16x32_bf16(afrag[1][kt], b, acc[1][nt], 0, 0, 0);
        }
    }

    // C/D layout: col = lane&15, row = (lane>>4)*4 + reg
    float bcol[8];
    #pragma unroll
    for (int nt = 0; nt < 8; nt++) bcol[nt] = bias[nt * 16 + lr];

    #pragma unroll
    for (int rt = 0; rt < 2; rt++) {
        int row0 = m_base + rt * 16 + lq * 4;
        #pragma unroll
        for (int i2 = 0; i2 < 4; i2++) {
            int r = row0 + i2;
            if (r < N) {
                if (mode == 0) {
                    float dr = dinv[r];
                    #pragma unroll
                    for (int nt = 0; nt < 8; nt++) {
                        int col = nt * 16 + lr;
                        float val = fmaxf(acc[rt][nt][i2] + bcol[nt], 0.0f);
                        hb_out[(size_t)r * D + col] = f2bf(val * dr);
                    }
                } else {
                    #pragma unroll
                    for (int nt = 0; nt < 8; nt++) {
                        int col = nt * 16 + lr;
                        hrelu[(size_t)r * D + col] = fmaxf(acc[rt][nt][i2] + bcol[nt], 0.0f);
                    }
                }
            }
        }
    }
}

// ---- segmented pooling: batch is sorted, so graph g owns rows [gstart, gstart+cnt) ----
__global__ __launch_bounds__(256) void k_pool(const float* __restrict__ hrelu,
                                              const int* __restrict__ gstart,
                                              const int* __restrict__ gcnt,
                                              float* __restrict__ gmax,
                                              float* __restrict__ gsum) {
    int g = blockIdx.x;
    int c = threadIdx.x & 127;
    int p = threadIdx.x >> 7;          // 2 row-parities x 128 cols
    int start = gstart[g];
    int endr = start + gcnt[g];

    float mx0 = 0.f, mx1 = 0.f, sm0 = 0.f, sm1 = 0.f;
    int r = start + p;
    for (; r + 2 < endr; r += 4) {
        float v0 = hrelu[(size_t)r * D + c];
        float v1 = hrelu[(size_t)(r + 2) * D + c];
        mx0 = fmaxf(mx0, v0); sm0 += v0;
        mx1 = fmaxf(mx1, v1); sm1 += v1;
    }
    if (r < endr) {
        float v0 = hrelu[(size_t)r * D + c];
        mx0 = fmaxf(mx0, v0); sm0 += v0;
    }
    float mx = fmaxf(mx0, mx1), sm = sm0 + sm1;

    __shared__ float smx[128], ssm[128];
    if (p == 1) { smx[c] = mx; ssm[c] = sm; }
    __syncthreads();
    if (p == 0) {
        gmax[g * D + c] = fmaxf(mx, smx[c]);
        gsum[g * D + c] = sm + ssm[c];
    }
}

// ---- final: out[g] = [gmax, gsum/cnt, gsum] @ out_w + out_b ----
__global__ void k_final(const float* __restrict__ gmax, const float* __restrict__ gsum,
                        const int* __restrict__ gcnt, const float* __restrict__ ow,
                        const float* __restrict__ ob, float* __restrict__ out) {
    int g = blockIdx.x;
    int t = threadIdx.x;  // 64
    float part[10];
    #pragma unroll
    for (int o = 0; o < 10; o++) part[o] = 0.f;
    float invc = 1.0f / fmaxf((float)gcnt[g], 1.0f);
    for (int k = t; k < 3 * D; k += 64) {
        float pk;
        if (k < D) pk = gmax[g * D + k];
        else if (k < 2 * D) pk = gsum[g * D + (k - D)] * invc;
        else pk = gsum[g * D + (k - 2 * D)];
        const float* w = ow + k * 10;
        #pragma unroll
        for (int o = 0; o < 10; o++) part[o] += pk * w[o];
    }
    #pragma unroll
    for (int off = 32; off > 0; off >>= 1)
        #pragma unroll
        for (int o = 0; o < 10; o++) part[o] += __shfl_down(part[o], off, 64);
    if (t == 0)
        #pragma unroll
        for (int o = 0; o < 10; o++) out[g * 10 + o] = part[o] + ob[o];
}

extern "C" void kernel_launch(void* const* d_in, const int* in_sizes, int n_in,
                              void* d_out, int out_size, void* d_ws, size_t ws_size,
                              hipStream_t stream) {
    const float* x     = (const float*)d_in[0];
    const int*   ei    = (const int*)d_in[1];
    const int*   batch = (const int*)d_in[2];
    const float* convw = (const float*)d_in[3];
    const float* convb = (const float*)d_in[4];
    const float* outw  = (const float*)d_in[5];
    const float* outb  = (const float*)d_in[6];
    float* out = (float*)d_out;

    const int N = in_sizes[0] / D;        // 100000
    const int E = in_sizes[1] / 2;        // 1600000
    const int L = in_sizes[3] / (D * D);  // 3
    const int B = out_size / 10;          // 256

    const int* src = ei;
    const int* dst = ei + E;

    const int NK  = N * NP;               // bucketed key space
    const int dpp = (N + 7) / 8;          // dst per partition
    const int spp = (N + NP - 1) / NP;    // src per pass-range

    char* p = (char*)d_ws;
    auto alloc = [&](size_t bytes) { char* r = p; p += (bytes + 255) & ~255ull; return r; };
    short* hb      = (short*)alloc((size_t)N * D * 2);      // bf16 pre-scaled feature rows
    short* gbuf    = (short*)alloc((size_t)N * D * 2);      // bf16 aggregated rows (GEMM input)
    float* hrelu   = (float*)alloc((size_t)N * D * 4);      // fp32 last-layer relu (pooling input)
    short* Wt      = (short*)alloc((size_t)L * D * D * 2);  // bf16 W^T
    int*   counts  = (int*)alloc((size_t)NK * 4);
    int*   row_ptr = (int*)alloc(((size_t)NK + 1) * 4);
    int*   cursor  = (int*)alloc((size_t)NK * 4);
    int*   csr_src = (int*)alloc((size_t)E * 4);
    int*   bs1     = (int*)alloc(4096 * 4);
    int*   excl1   = (int*)alloc(4096 * 4);
    int*   bs2     = (int*)alloc(64 * 4);
    int*   boffs2  = (int*)alloc(64 * 4);
    float* dinv    = (float*)alloc((size_t)N * 4);
    float* gmax    = (float*)alloc((size_t)B * D * 4);
    float* gsum    = (float*)alloc((size_t)B * D * 4);
    int*   gcnt    = (int*)alloc((size_t)B * 4);
    int*   gstart  = (int*)alloc(((size_t)B + 1) * 4);

    hipMemsetAsync(counts, 0, (size_t)NK * 4, stream);

    const int nb0 = (NK + 255) / 256;          // 3125
    const int nb1 = (nb0 + 255) / 256;         // 13
    const int eblocks = 8 * ((E + 255) / 256); // XCD-partitioned edge kernels

    k_count<<<eblocks, 256, 0, stream>>>(src, dst, counts, E, dpp, spp);
    k_gseg<<<1, 512, 0, stream>>>(batch, gstart, N, B);
    k_gcnt_seg<<<1, 256, 0, stream>>>(gstart, gcnt, B);
    // 3-level scan: counts[NK] -> row_ptr (exclusive)
    k_scan1<<<nb0, 256, 0, stream>>>(counts, row_ptr, bs1, NK);
    k_scan1<<<nb1, 256, 0, stream>>>(bs1, excl1, bs2, nb0);
    k_scan2<<<1, 512, 0, stream>>>(bs2, boffs2, nb1);
    k_scan_add<<<nb1, 256, 0, stream>>>(excl1, boffs2, nb0);
    k_scan3<<<nb0, 256, 0, stream>>>(row_ptr, cursor, excl1, NK, E);
    k_dinv<<<(N + 255) / 256, 256, 0, stream>>>(row_ptr, dinv, N);
    k_fill<<<eblocks, 256, 0, stream>>>(src, dst, cursor, csr_src, E, dpp, spp);
    k_cvt_x<<<((N * D / 4) + 255) / 256, 256, 0, stream>>>(x, dinv, hb, N * D / 4);
    k_cvt_w<<<((L * D * D) + 255) / 256, 256, 0, stream>>>(convw, Wt, L * D * D);

    const int ablocks = (N + 15) / 16;
    const int gblocks = (N + 127) / 128;
    for (int l = 0; l < L; l++) {
        k_aggregate<<<ablocks, 256, 0, stream>>>(hb, row_ptr, csr_src, dinv, gbuf, N);
        k_gemm<<<gblocks, 256, 0, stream>>>(gbuf, Wt + l * D * D, convb + (size_t)l * D,
                                            dinv, hb, hrelu, N, (l == L - 1) ? 1 : 0);
    }
    k_pool<<<B, 256, 0, stream>>>(hrelu, gstart, gcnt, gmax, gsum);
    k_final<<<B, 64, 0, stream>>>(gmax, gsum, gcnt, outw, outb, out);
}